// Round 6
// baseline (275.955 us; speedup 1.0000x reference)
//
#include <hip/hip_runtime.h>
#include <hip/hip_bf16.h>

// CrossAttentionHead: B=8, S=2048, E=768, H=128. fp32 inputs AND fp32 output.
// q=x@Wq+bq; k=x@Wk+bk; v=x@Wv+bv; out = softmax(q k^T / sqrt(768)) @ v
// enc_output (d_in[1]) unused. Intermediates bf16, accum fp32.
// R6: latency hiding. qkv: ping-pong LDS double-buffer (prefetch tile t+1 to
//     regs during compute of t). flash: register prefetch of next K/V tile
//     (LDS dbuf would cost occupancy 3->1 blocks/CU).

typedef __bf16 bf16x8 __attribute__((ext_vector_type(8)));
typedef float f32x4 __attribute__((ext_vector_type(4)));
using bf16 = __hip_bfloat16;

#define EMB 768
#define HD 128
#define SEQ 2048
#define BATCH 8
#define ROWS (BATCH * SEQ)   // 16384
#define NSPLIT 4
#define TILES_PER_SPLIT (SEQ / 64 / NSPLIT)  // 8

// convert 8 fp32 -> 8 bf16, single 16B store
__device__ inline void cvt_store8(bf16* dst, float4 a, float4 b) {
    union { bf16 h[8]; uint4 u; } t;
    t.h[0] = __float2bfloat16(a.x); t.h[1] = __float2bfloat16(a.y);
    t.h[2] = __float2bfloat16(a.z); t.h[3] = __float2bfloat16(a.w);
    t.h[4] = __float2bfloat16(b.x); t.h[5] = __float2bfloat16(b.y);
    t.h[6] = __float2bfloat16(b.z); t.h[7] = __float2bfloat16(b.w);
    *reinterpret_cast<uint4*>(dst) = t.u;
}

// ---------------------------------------------------------------- W transpose
__global__ __launch_bounds__(256) void wt_kernel(
    const float* __restrict__ Wq, const float* __restrict__ Wk,
    const float* __restrict__ Wv, bf16* __restrict__ Wt)
{
    __shared__ float t_lds[32][33];
    const int tid = threadIdx.x;
    const int k0 = blockIdx.x * 32;
    const int n0 = blockIdx.y * 32;
    const int mtx = blockIdx.z;
    const float* W = (mtx == 0) ? Wq : (mtx == 1) ? Wk : Wv;
    const int j = tid & 31, i0 = tid >> 5;
#pragma unroll
    for (int c = 0; c < 4; ++c)
        t_lds[i0 + 8 * c][j] = W[(size_t)(k0 + i0 + 8 * c) * HD + n0 + j];
    __syncthreads();
#pragma unroll
    for (int c = 0; c < 4; ++c)
        Wt[(size_t)mtx * HD * EMB + (size_t)(n0 + i0 + 8 * c) * EMB + k0 + j] =
            __float2bfloat16(t_lds[j][i0 + 8 * c]);
}

// ---------------------------------------------------------------- QKV GEMM
// grid (256 row-tiles, 3 sel), block 256 (4 waves). Tile 64(M)x128(N), BK=64.
// Ping-pong LDS double buffer; prefetch t+1 into regs while computing t.
__global__ __launch_bounds__(256) void qkv_kernel(
    const float* __restrict__ x, const bf16* __restrict__ Wt,
    const float* __restrict__ bq, const float* __restrict__ bk,
    const float* __restrict__ bv,
    bf16* __restrict__ Q, bf16* __restrict__ K, bf16* __restrict__ Vt)
{
    __shared__ alignas(16) bf16 a_lds[2][64][68];    // 2 x 8.7 KB
    __shared__ alignas(16) bf16 b_lds[2][128][68];   // 2 x 17.4 KB
    const int tid  = threadIdx.x;
    const int sel  = blockIdx.y;
    const int row0 = blockIdx.x * 64;
    const bf16* Wsel = Wt + (size_t)sel * HD * EMB;
    const int lane = tid & 63, wave = tid >> 6;
    const int lr = lane & 15, lq = lane >> 4;

    float4 fa[2][2];
    uint4  fb[4];

    auto load_regs = [&](int kt) {
#pragma unroll
        for (int c = 0; c < 2; ++c) {                 // x: 64 rows x 64 cols fp32
            int lin = tid + c * 256;
            int r = lin >> 3, ch = lin & 7;
            const float* src = &x[(size_t)(row0 + r) * EMB + kt * 64 + ch * 8];
            fa[c][0] = *reinterpret_cast<const float4*>(src);
            fa[c][1] = *reinterpret_cast<const float4*>(src + 4);
        }
#pragma unroll
        for (int c = 0; c < 4; ++c) {                 // W: 128 n x 64 k bf16
            int lin = tid + c * 256;
            int r = lin >> 3, ch = lin & 7;
            fb[c] = *reinterpret_cast<const uint4*>(&Wsel[(size_t)r * EMB + kt * 64 + ch * 8]);
        }
    };
    auto store_lds = [&](int buf) {
#pragma unroll
        for (int c = 0; c < 2; ++c) {
            int lin = tid + c * 256;
            int r = lin >> 3, ch = lin & 7;
            cvt_store8(&a_lds[buf][r][ch * 8], fa[c][0], fa[c][1]);
        }
#pragma unroll
        for (int c = 0; c < 4; ++c) {
            int lin = tid + c * 256;
            int r = lin >> 3, ch = lin & 7;
            *reinterpret_cast<uint4*>(&b_lds[buf][r][ch * 8]) = fb[c];
        }
    };

    f32x4 acc[8];
#pragma unroll
    for (int j = 0; j < 8; ++j) acc[j] = f32x4{0.f, 0.f, 0.f, 0.f};

    load_regs(0);
    store_lds(0);
    __syncthreads();

    for (int kt = 0; kt < EMB / 64; ++kt) {
        const int cur = kt & 1;
        if (kt < EMB / 64 - 1) load_regs(kt + 1);     // in flight during compute
#pragma unroll
        for (int ks = 0; ks < 2; ++ks) {
            bf16x8 a = *reinterpret_cast<const bf16x8*>(&a_lds[cur][wave * 16 + lr][ks * 32 + lq * 8]);
#pragma unroll
            for (int nt = 0; nt < 8; ++nt) {
                bf16x8 b = *reinterpret_cast<const bf16x8*>(&b_lds[cur][nt * 16 + lr][ks * 32 + lq * 8]);
                acc[nt] = __builtin_amdgcn_mfma_f32_16x16x32_bf16(a, b, acc[nt], 0, 0, 0);
            }
        }
        if (kt < EMB / 64 - 1) {
            __syncthreads();                          // all reads of next buf's prev contents done
            store_lds(1 - cur);
            __syncthreads();
        }
    }

    // Epilogue through LDS; o_lds aliases b_lds[0] (final compute used buf 1)
    bf16 (*o_lds)[132] = reinterpret_cast<bf16(*)[132]>(&b_lds[0][0][0]);
    const float* bias = (sel == 0) ? bq : (sel == 1) ? bk : bv;
#pragma unroll
    for (int nt = 0; nt < 8; ++nt) {
        int col = nt * 16 + lr;
        float bb = bias[col];
#pragma unroll
        for (int rg = 0; rg < 4; ++rg)                // C/D: col=lane&15, row=(lane>>4)*4+reg
            o_lds[wave * 16 + lq * 4 + rg][col] = __float2bfloat16(acc[nt][rg] + bb);
    }
    __syncthreads();
    if (sel < 2) {
        bf16* dst = (sel == 0) ? Q : K;
#pragma unroll
        for (int c = 0; c < 4; ++c) {
            int lin = tid + c * 256;
            int r = lin >> 4, ch = lin & 15;
            *reinterpret_cast<uint4*>(&dst[(size_t)(row0 + r) * HD + ch * 8]) =
                *reinterpret_cast<const uint4*>(&o_lds[r][ch * 8]);
        }
    } else {
        int d = tid >> 1, sh = (tid & 1) * 32;
        int bi = row0 >> 11, s0 = row0 & (SEQ - 1);
        union { bf16 h[32]; uint4 u4[4]; } pk;
#pragma unroll
        for (int s = 0; s < 32; ++s) pk.h[s] = o_lds[sh + s][d];
        bf16* base = &Vt[((size_t)bi * HD + d) * SEQ + s0 + sh];
#pragma unroll
        for (int c = 0; c < 4; ++c)
            *reinterpret_cast<uint4*>(base + c * 8) = pk.u4[c];
    }
}

// ---------------------------------------------------------------- flash attn (split-K, S^T)
// grid (32 q-tiles, 8 batches, 4 splits) = 1024 blocks; block 256 = 4 waves x 16 q.
// S^T = K q^T (fixed-shift exp2), O^T = V^T P^T; l via ones-row at d=128.
// Register prefetch of next K/V tile overlaps global latency with compute.
__global__ __launch_bounds__(256) void flash_kernel(
    const bf16* __restrict__ Q, const bf16* __restrict__ K,
    const bf16* __restrict__ Vt,
    float* __restrict__ Opart, float* __restrict__ Lpart)
{
    __shared__ alignas(16) bf16 k_lds[64][132];    // [krow][d]
    __shared__ alignas(16) bf16 v_lds[144][68];    // [d][krow]; rows 128..143: ones/zeros
    __shared__ alignas(16) bf16 p_lds[4][16][72];  // per-wave P^T [q][k]
    const int tid = threadIdx.x;
    const int lane = tid & 63, wave = tid >> 6;
    const int lr = lane & 15, lq = lane >> 4;
    const int b  = blockIdx.y;
    const int split = blockIdx.z;
    const int q0 = blockIdx.x * 64;
    const int qrow = b * SEQ + q0 + wave * 16;

    const float sc = 0.03608439182435161f * 1.44269504088896f; // 1/sqrt(768)*log2(e)

    // ones-row block for l: v_lds row 128 = 1.0, rows 129..143 = 0 (written once)
    for (int i = tid; i < 16 * 68; i += 256) {
        int r = i / 68, c = i % 68;
        v_lds[128 + r][c] = __float2bfloat16(r == 0 ? 1.0f : 0.0f);
    }

    bf16x8 qf[4];
#pragma unroll
    for (int ks = 0; ks < 4; ++ks)
        qf[ks] = *reinterpret_cast<const bf16x8*>(&Q[(size_t)(qrow + lr) * HD + ks * 32 + lq * 8]);

    uint4 rk[4], rv[4];
    auto load_kv = [&](int t) {
#pragma unroll
        for (int c = 0; c < 4; ++c) {              // K tile: 64 rows x 128 d
            int lin = tid + c * 256;
            int r = lin >> 4, ch = lin & 15;
            rk[c] = *reinterpret_cast<const uint4*>(&K[(size_t)(b * SEQ + t * 64 + r) * HD + ch * 8]);
        }
#pragma unroll
        for (int c = 0; c < 4; ++c) {              // Vt tile: 128 d x 64 krow
            int lin = tid + c * 256;
            int r = lin >> 3, ch = lin & 7;
            rv[c] = *reinterpret_cast<const uint4*>(&Vt[((size_t)b * HD + r) * SEQ + t * 64 + ch * 8]);
        }
    };

    f32x4 o[9];
#pragma unroll
    for (int d = 0; d < 9; ++d) o[d] = f32x4{0.f, 0.f, 0.f, 0.f};

    load_kv(split * TILES_PER_SPLIT);

    for (int i = 0; i < TILES_PER_SPLIT; ++i) {
        __syncthreads();                           // prev iter's LDS reads done (covers init too)
#pragma unroll
        for (int c = 0; c < 4; ++c) {
            int lin = tid + c * 256;
            int r = lin >> 4, ch = lin & 15;
            *reinterpret_cast<uint4*>(&k_lds[r][ch * 8]) = rk[c];
        }
#pragma unroll
        for (int c = 0; c < 4; ++c) {
            int lin = tid + c * 256;
            int r = lin >> 3, ch = lin & 7;
            *reinterpret_cast<uint4*>(&v_lds[r][ch * 8]) = rv[c];
        }
        if (i + 1 < TILES_PER_SPLIT)               // next tile in flight during compute
            load_kv(split * TILES_PER_SPLIT + i + 1);
        __syncthreads();

        // S^T: s[nt]: lane holds q=lr, k=nt*16+lq*4+r
        f32x4 s[4];
#pragma unroll
        for (int nt = 0; nt < 4; ++nt) {
            s[nt] = f32x4{0.f, 0.f, 0.f, 0.f};
#pragma unroll
            for (int ks = 0; ks < 4; ++ks) {
                bf16x8 kf = *reinterpret_cast<const bf16x8*>(&k_lds[nt * 16 + lr][ks * 32 + lq * 8]);
                s[nt] = __builtin_amdgcn_mfma_f32_16x16x32_bf16(kf, qf[ks], s[nt], 0, 0, 0);
            }
        }

        // p = exp2(s*sc - 8); pack 4 consecutive k per nt -> one b64 write
#pragma unroll
        for (int nt = 0; nt < 4; ++nt) {
            union { bf16 h[4]; uint2 u; } pk;
#pragma unroll
            for (int r = 0; r < 4; ++r)
                pk.h[r] = __float2bfloat16(exp2f(__builtin_fmaf(s[nt][r], sc, -8.0f)));
            *reinterpret_cast<uint2*>(&p_lds[wave][lr][nt * 16 + lq * 4]) = pk.u;
        }
        // wave-private p region: no barrier needed

        // O^T += V^T P^T : rows = d (9 tiles, last = ones row -> l), cols = q
#pragma unroll
        for (int ks = 0; ks < 2; ++ks) {
            bf16x8 pf = *reinterpret_cast<const bf16x8*>(&p_lds[wave][lr][ks * 32 + lq * 8]);
#pragma unroll
            for (int d = 0; d < 9; ++d) {
                bf16x8 vf = *reinterpret_cast<const bf16x8*>(&v_lds[d * 16 + lr][ks * 32 + lq * 8]);
                o[d] = __builtin_amdgcn_mfma_f32_16x16x32_bf16(vf, pf, o[d], 0, 0, 0);
            }
        }
    }

    // O^T frag: q = lr, d = dtile*16 + lq*4 + reg  -> float4 stores
    const size_t obase = (size_t)split * ROWS;
#pragma unroll
    for (int d = 0; d < 8; ++d)
        *reinterpret_cast<f32x4*>(&Opart[(obase + qrow + lr) * HD + d * 16 + lq * 4]) = o[d];
    if (lane < 16)                                  // lq==0, reg 0 of tile 8 = l(q=lr)
        Lpart[obase + qrow + lr] = o[8][0];
}

// ---------------------------------------------------------------- combine
__global__ __launch_bounds__(256) void combine_kernel(
    const float* __restrict__ Opart, const float* __restrict__ Lpart,
    float* __restrict__ out)
{
    int gid = blockIdx.x * 256 + threadIdx.x;      // ROWS * 32
    int row = gid >> 5, dc = gid & 31;
    float L = 0.f;
#pragma unroll
    for (int s = 0; s < NSPLIT; ++s)
        L += Lpart[(size_t)s * ROWS + row];
    float4 acc = {0.f, 0.f, 0.f, 0.f};
#pragma unroll
    for (int s = 0; s < NSPLIT; ++s) {
        float4 v = *reinterpret_cast<const float4*>(&Opart[((size_t)s * ROWS + row) * HD + dc * 4]);
        acc.x += v.x; acc.y += v.y; acc.z += v.z; acc.w += v.w;
    }
    float inv = 1.f / L;
    acc.x *= inv; acc.y *= inv; acc.z *= inv; acc.w *= inv;
    *reinterpret_cast<float4*>(&out[(size_t)row * HD + dc * 4]) = acc;
}

// ---------------------------------------------------------------- launch
extern "C" void kernel_launch(void* const* d_in, const int* in_sizes, int n_in,
                              void* d_out, int out_size, void* d_ws, size_t ws_size,
                              hipStream_t stream) {
    const float* x  = (const float*)d_in[0];
    const float* Wq = (const float*)d_in[2];
    const float* bq = (const float*)d_in[3];
    const float* Wk = (const float*)d_in[4];
    const float* bk = (const float*)d_in[5];
    const float* Wv = (const float*)d_in[6];
    const float* bv = (const float*)d_in[7];
    float* out = (float*)d_out;

    char* ws = (char*)d_ws;
    const size_t WT_BYTES  = (size_t)3 * HD * EMB * 2;
    const size_t QKV_BYTES = (size_t)ROWS * HD * 2;
    const size_t OP_BYTES  = (size_t)NSPLIT * ROWS * HD * 4;
    bf16*  Wt    = (bf16*)ws;
    bf16*  Qb    = (bf16*)(ws + WT_BYTES);
    bf16*  Kb    = (bf16*)(ws + WT_BYTES + QKV_BYTES);
    bf16*  Vt    = (bf16*)(ws + WT_BYTES + 2 * QKV_BYTES);
    float* Opart = (float*)(ws + WT_BYTES + 3 * QKV_BYTES);
    float* Lpart = (float*)(ws + WT_BYTES + 3 * QKV_BYTES + OP_BYTES);

    hipLaunchKernelGGL(wt_kernel, dim3(EMB / 32, HD / 32, 3), dim3(256), 0, stream,
                       Wq, Wk, Wv, Wt);
    hipLaunchKernelGGL(qkv_kernel, dim3(ROWS / 64, 3), dim3(256), 0, stream,
                       x, Wt, bq, bk, bv, Qb, Kb, Vt);
    hipLaunchKernelGGL(flash_kernel, dim3(SEQ / 64, BATCH, NSPLIT), dim3(256), 0, stream,
                       Qb, Kb, Vt, Opart, Lpart);
    hipLaunchKernelGGL(combine_kernel, dim3(ROWS * 32 / 256), dim3(256), 0, stream,
                       Opart, Lpart, out);
}

// Round 7
// 229.287 us; speedup vs baseline: 1.2035x; 1.2035x over previous
//
#include <hip/hip_runtime.h>
#include <hip/hip_bf16.h>

// CrossAttentionHead: B=8, S=2048, E=768, H=128. fp32 inputs AND fp32 output.
// q=x@Wq+bq; k=x@Wk+bk; v=x@Wv+bv; out = softmax(q k^T / sqrt(768)) @ v
// enc_output (d_in[1]) unused. Intermediates bf16, accum fp32.
// R7: NO manual prefetch (R6 spilled: WRITE_SIZE 181MB). Structural overlap:
//  - flash k-split: waves own 16 k-rows -> K frags from global regs (no K LDS,
//    no K barrier); Q re-read per tile (L1/L2-hot); only V staged in LDS.
//    LDS 27.6KB -> grid's 4 blocks/CU fully resident. 2 barriers/tile.
//  - qkv: R5 structure, M-tile 32 -> 1536 blocks = 6/CU (24 waves/CU TLP).

typedef __bf16 bf16x8 __attribute__((ext_vector_type(8)));
typedef float f32x4 __attribute__((ext_vector_type(4)));
using bf16 = __hip_bfloat16;

#define EMB 768
#define HD 128
#define SEQ 2048
#define BATCH 8
#define ROWS (BATCH * SEQ)   // 16384
#define NSPLIT 4
#define TILES_PER_SPLIT (SEQ / 64 / NSPLIT)  // 8

// convert 8 fp32 -> 8 bf16, single 16B store
__device__ inline void cvt_store8(bf16* dst, float4 a, float4 b) {
    union { bf16 h[8]; uint4 u; } t;
    t.h[0] = __float2bfloat16(a.x); t.h[1] = __float2bfloat16(a.y);
    t.h[2] = __float2bfloat16(a.z); t.h[3] = __float2bfloat16(a.w);
    t.h[4] = __float2bfloat16(b.x); t.h[5] = __float2bfloat16(b.y);
    t.h[6] = __float2bfloat16(b.z); t.h[7] = __float2bfloat16(b.w);
    *reinterpret_cast<uint4*>(dst) = t.u;
}

// ---------------------------------------------------------------- W transpose
__global__ __launch_bounds__(256) void wt_kernel(
    const float* __restrict__ Wq, const float* __restrict__ Wk,
    const float* __restrict__ Wv, bf16* __restrict__ Wt)
{
    __shared__ float t_lds[32][33];
    const int tid = threadIdx.x;
    const int k0 = blockIdx.x * 32;
    const int n0 = blockIdx.y * 32;
    const int mtx = blockIdx.z;
    const float* W = (mtx == 0) ? Wq : (mtx == 1) ? Wk : Wv;
    const int j = tid & 31, i0 = tid >> 5;
#pragma unroll
    for (int c = 0; c < 4; ++c)
        t_lds[i0 + 8 * c][j] = W[(size_t)(k0 + i0 + 8 * c) * HD + n0 + j];
    __syncthreads();
#pragma unroll
    for (int c = 0; c < 4; ++c)
        Wt[(size_t)mtx * HD * EMB + (size_t)(n0 + i0 + 8 * c) * EMB + k0 + j] =
            __float2bfloat16(t_lds[j][i0 + 8 * c]);
}

// ---------------------------------------------------------------- QKV GEMM
// grid (512 row-tiles, 3 sel), block 256 (4 waves). Tile 32(M)x128(N), BK=64.
// wave w: rows strip (w&1)*16, N half (w>>1)*64.
__global__ __launch_bounds__(256) void qkv_kernel(
    const float* __restrict__ x, const bf16* __restrict__ Wt,
    const float* __restrict__ bq, const float* __restrict__ bk,
    const float* __restrict__ bv,
    bf16* __restrict__ Q, bf16* __restrict__ K, bf16* __restrict__ Vt)
{
    __shared__ alignas(16) bf16 a_lds[32][72];     // 4.6 KB (pad 8, 16B-aligned rows)
    __shared__ alignas(16) bf16 b_lds[128][72];    // 18.4 KB
    const int tid  = threadIdx.x;
    const int sel  = blockIdx.y;
    const int row0 = blockIdx.x * 32;
    const bf16* Wsel = Wt + (size_t)sel * HD * EMB;
    const int lane = tid & 63, wave = tid >> 6;
    const int lr = lane & 15, lq = lane >> 4;
    const int mstrip = (wave & 1) * 16;            // row strip within tile
    const int nhalf  = (wave >> 1) * 64;           // N half

    f32x4 acc[4];
#pragma unroll
    for (int j = 0; j < 4; ++j) acc[j] = f32x4{0.f, 0.f, 0.f, 0.f};

    for (int kt = 0; kt < EMB / 64; ++kt) {
        {                                           // x tile: 32 rows x 64 cols fp32
            int r = tid >> 3, ch = tid & 7;
            const float* src = &x[(size_t)(row0 + r) * EMB + kt * 64 + ch * 8];
            float4 f0 = *reinterpret_cast<const float4*>(src);
            float4 f1 = *reinterpret_cast<const float4*>(src + 4);
            cvt_store8(&a_lds[r][ch * 8], f0, f1);
        }
#pragma unroll
        for (int c = 0; c < 4; ++c) {               // W tile: 128 n x 64 k bf16
            int lin = tid + c * 256;
            int r = lin >> 3, ch = lin & 7;
            *reinterpret_cast<uint4*>(&b_lds[r][ch * 8]) =
                *reinterpret_cast<const uint4*>(&Wsel[(size_t)r * EMB + kt * 64 + ch * 8]);
        }
        __syncthreads();
#pragma unroll
        for (int ks = 0; ks < 2; ++ks) {
            bf16x8 a = *reinterpret_cast<const bf16x8*>(&a_lds[mstrip + lr][ks * 32 + lq * 8]);
#pragma unroll
            for (int nt = 0; nt < 4; ++nt) {
                bf16x8 b = *reinterpret_cast<const bf16x8*>(&b_lds[nhalf + nt * 16 + lr][ks * 32 + lq * 8]);
                acc[nt] = __builtin_amdgcn_mfma_f32_16x16x32_bf16(a, b, acc[nt], 0, 0, 0);
            }
        }
        __syncthreads();
    }

    // Epilogue through LDS; o_lds aliases b_lds
    bf16 (*o_lds)[132] = reinterpret_cast<bf16(*)[132]>(&b_lds[0][0]);  // 32x132 <= 128x72
    const float* bias = (sel == 0) ? bq : (sel == 1) ? bk : bv;
#pragma unroll
    for (int nt = 0; nt < 4; ++nt) {
        int col = nhalf + nt * 16 + lr;
        float bb = bias[col];
#pragma unroll
        for (int rg = 0; rg < 4; ++rg)              // C/D: col=lane&15, row=(lane>>4)*4+reg
            o_lds[mstrip + lq * 4 + rg][col] = __float2bfloat16(acc[nt][rg] + bb);
    }
    __syncthreads();
    if (sel < 2) {                                  // coalesced row-major, 32B/thread
        bf16* dst = (sel == 0) ? Q : K;
        int r = tid >> 3, ch = (tid & 7) * 16;
        *reinterpret_cast<uint4*>(&dst[(size_t)(row0 + r) * HD + ch]) =
            *reinterpret_cast<const uint4*>(&o_lds[r][ch]);
        *reinterpret_cast<uint4*>(&dst[(size_t)(row0 + r) * HD + ch + 8]) =
            *reinterpret_cast<const uint4*>(&o_lds[r][ch + 8]);
    } else {                                        // transpose: Vt[b][d][s], 32B/thread
        int d = tid >> 1, sh = (tid & 1) * 16;
        int bi = row0 >> 11, s0 = row0 & (SEQ - 1);
        union { bf16 h[16]; uint4 u4[2]; } pk;
#pragma unroll
        for (int s = 0; s < 16; ++s) pk.h[s] = o_lds[sh + s][d];
        bf16* base = &Vt[((size_t)bi * HD + d) * SEQ + s0 + sh];
        *reinterpret_cast<uint4*>(base)     = pk.u4[0];
        *reinterpret_cast<uint4*>(base + 8) = pk.u4[1];
    }
}

// ---------------------------------------------------------------- flash attn (split-K, k-split waves)
// grid (32 q-tiles, 8 batches, 4 splits) = 1024 blocks; block 256 = 4 waves.
// Wave w owns k-rows [16w,16w+16) of each tile (K frags from global, regs) and
// d-rows [32w,32w+32) of O^T. Q re-read per tile from global (L1/L2-hot).
// Only V staged in LDS. S^T = K q^T, p = exp2(s*sc - 8) (fixed shift).
__global__ __launch_bounds__(256, 4) void flash_kernel(
    const bf16* __restrict__ Q, const bf16* __restrict__ K,
    const bf16* __restrict__ Vt,
    float* __restrict__ Opart, float* __restrict__ Lpart)
{
    __shared__ alignas(16) bf16 v_lds[128][72];    // [d][krow], 18.4 KB
    __shared__ alignas(16) bf16 p_lds[64][72];     // [q][krow], 9.2 KB (k-cols wave-disjoint)
    const int tid = threadIdx.x;
    const int lane = tid & 63, wave = tid >> 6;
    const int lr = lane & 15, lq = lane >> 4;
    const int b  = blockIdx.y;
    const int split = blockIdx.z;
    const int q0 = blockIdx.x * 64;
    const int qbase = b * SEQ + q0;                // block's global q base

    const float sc = 0.03608439182435161f * 1.44269504088896f; // 1/sqrt(768)*log2(e)

    f32x4 o[2][4];                                  // [dt][qt]
#pragma unroll
    for (int dt = 0; dt < 2; ++dt)
#pragma unroll
        for (int qt = 0; qt < 4; ++qt) o[dt][qt] = f32x4{0.f, 0.f, 0.f, 0.f};
    float lsum[4] = {0.f, 0.f, 0.f, 0.f};           // per-lane partial l, per qt

    for (int i = 0; i < TILES_PER_SPLIT; ++i) {
        const int t = split * TILES_PER_SPLIT + i;
        // V tile -> regs (issued first; drained by the kf/qf waits below at no cost)
        uint4 rv[4];
#pragma unroll
        for (int c = 0; c < 4; ++c) {               // Vt tile: 128 d x 64 krow
            int lin = tid + c * 256;
            int r = lin >> 3, ch = lin & 7;
            rv[c] = *reinterpret_cast<const uint4*>(&Vt[((size_t)b * HD + r) * SEQ + t * 64 + ch * 8]);
        }
        // K frags: wave-own 16 k-rows, straight to regs (A-layout: m=lr, k=lq*8+j)
        bf16x8 kf[4];
#pragma unroll
        for (int ks = 0; ks < 4; ++ks)
            kf[ks] = *reinterpret_cast<const bf16x8*>(
                &K[(size_t)(b * SEQ + t * 64 + wave * 16 + lr) * HD + ks * 32 + lq * 8]);

        // QK per q-tile: S^T[k=16w..][q] ; then p -> p_lds
#pragma unroll
        for (int qt = 0; qt < 4; ++qt) {
            f32x4 s = f32x4{0.f, 0.f, 0.f, 0.f};
#pragma unroll
            for (int ks = 0; ks < 4; ++ks) {
                bf16x8 qf = *reinterpret_cast<const bf16x8*>(
                    &Q[(size_t)(qbase + qt * 16 + lr) * HD + ks * 32 + lq * 8]);
                s = __builtin_amdgcn_mfma_f32_16x16x32_bf16(kf[ks], qf, s, 0, 0, 0);
            }
            union { bf16 h[4]; uint2 u; } pk;
            float rs = 0.f;
#pragma unroll
            for (int r = 0; r < 4; ++r) {
                bf16 pv = __float2bfloat16(exp2f(__builtin_fmaf(s[r], sc, -8.0f)));
                pk.h[r] = pv;
                rs += __bfloat162float(pv);
            }
            lsum[qt] += rs;
            // lane holds q=qt*16+lr, k=16*wave+lq*4+r
            *reinterpret_cast<uint2*>(&p_lds[qt * 16 + lr][wave * 16 + lq * 4]) = pk.u;
        }

        // V regs -> LDS (v loads complete by now; no extra stall)
#pragma unroll
        for (int c = 0; c < 4; ++c) {
            int lin = tid + c * 256;
            int r = lin >> 3, ch = lin & 7;
            *reinterpret_cast<uint4*>(&v_lds[r][ch * 8]) = rv[c];
        }
        __syncthreads();                            // P + V visible to all waves

        // PV: O^T[d][q] += V^T[d][k] P[q][k]^T ; wave owns d-rows 32w..32w+31
#pragma unroll
        for (int ks = 0; ks < 2; ++ks) {
#pragma unroll
            for (int dt = 0; dt < 2; ++dt) {
                bf16x8 vf = *reinterpret_cast<const bf16x8*>(
                    &v_lds[wave * 32 + dt * 16 + lr][ks * 32 + lq * 8]);
#pragma unroll
                for (int qt = 0; qt < 4; ++qt) {
                    bf16x8 pf = *reinterpret_cast<const bf16x8*>(
                        &p_lds[qt * 16 + lr][ks * 32 + lq * 8]);
                    o[dt][qt] = __builtin_amdgcn_mfma_f32_16x16x32_bf16(vf, pf, o[dt][qt], 0, 0, 0);
                }
            }
        }
        __syncthreads();                            // PV done before next tile overwrites
    }

    // O^T frag: lane(lr,lq) holds q=qbase+qt*16+lr, d=32w+dt*16+lq*4+{0..3}
    const size_t obase = (size_t)split * ROWS;
#pragma unroll
    for (int dt = 0; dt < 2; ++dt)
#pragma unroll
        for (int qt = 0; qt < 4; ++qt)
            *reinterpret_cast<f32x4*>(
                &Opart[(obase + qbase + qt * 16 + lr) * HD + wave * 32 + dt * 16 + lq * 4]) = o[dt][qt];

    // l: reduce over lq (k within wave), then across waves via LDS
#pragma unroll
    for (int qt = 0; qt < 4; ++qt) {
        lsum[qt] += __shfl_xor(lsum[qt], 16);
        lsum[qt] += __shfl_xor(lsum[qt], 32);
    }
    float* red = reinterpret_cast<float*>(&p_lds[0][0]);   // reuse (past last barrier)
    if (lq == 0) {
#pragma unroll
        for (int qt = 0; qt < 4; ++qt)
            red[wave * 64 + qt * 16 + lr] = lsum[qt];
    }
    __syncthreads();
    if (wave == 0) {
        float L = red[lane] + red[64 + lane] + red[128 + lane] + red[192 + lane];
        Lpart[obase + qbase + lane] = L;
    }
}

// ---------------------------------------------------------------- combine
__global__ __launch_bounds__(256) void combine_kernel(
    const float* __restrict__ Opart, const float* __restrict__ Lpart,
    float* __restrict__ out)
{
    int gid = blockIdx.x * 256 + threadIdx.x;      // ROWS * 32
    int row = gid >> 5, dc = gid & 31;
    float L = 0.f;
#pragma unroll
    for (int s = 0; s < NSPLIT; ++s)
        L += Lpart[(size_t)s * ROWS + row];
    float4 acc = {0.f, 0.f, 0.f, 0.f};
#pragma unroll
    for (int s = 0; s < NSPLIT; ++s) {
        float4 v = *reinterpret_cast<const float4*>(&Opart[((size_t)s * ROWS + row) * HD + dc * 4]);
        acc.x += v.x; acc.y += v.y; acc.z += v.z; acc.w += v.w;
    }
    float inv = 1.f / L;
    acc.x *= inv; acc.y *= inv; acc.z *= inv; acc.w *= inv;
    *reinterpret_cast<float4*>(&out[(size_t)row * HD + dc * 4]) = acc;
}

// ---------------------------------------------------------------- launch
extern "C" void kernel_launch(void* const* d_in, const int* in_sizes, int n_in,
                              void* d_out, int out_size, void* d_ws, size_t ws_size,
                              hipStream_t stream) {
    const float* x  = (const float*)d_in[0];
    const float* Wq = (const float*)d_in[2];
    const float* bq = (const float*)d_in[3];
    const float* Wk = (const float*)d_in[4];
    const float* bk = (const float*)d_in[5];
    const float* Wv = (const float*)d_in[6];
    const float* bv = (const float*)d_in[7];
    float* out = (float*)d_out;

    char* ws = (char*)d_ws;
    const size_t WT_BYTES  = (size_t)3 * HD * EMB * 2;
    const size_t QKV_BYTES = (size_t)ROWS * HD * 2;
    const size_t OP_BYTES  = (size_t)NSPLIT * ROWS * HD * 4;
    bf16*  Wt    = (bf16*)ws;
    bf16*  Qb    = (bf16*)(ws + WT_BYTES);
    bf16*  Kb    = (bf16*)(ws + WT_BYTES + QKV_BYTES);
    bf16*  Vt    = (bf16*)(ws + WT_BYTES + 2 * QKV_BYTES);
    float* Opart = (float*)(ws + WT_BYTES + 3 * QKV_BYTES);
    float* Lpart = (float*)(ws + WT_BYTES + 3 * QKV_BYTES + OP_BYTES);

    hipLaunchKernelGGL(wt_kernel, dim3(EMB / 32, HD / 32, 3), dim3(256), 0, stream,
                       Wq, Wk, Wv, Wt);
    hipLaunchKernelGGL(qkv_kernel, dim3(ROWS / 32, 3), dim3(256), 0, stream,
                       x, Wt, bq, bk, bv, Qb, Kb, Vt);
    hipLaunchKernelGGL(flash_kernel, dim3(SEQ / 64, BATCH, NSPLIT), dim3(256), 0, stream,
                       Qb, Kb, Vt, Opart, Lpart);
    hipLaunchKernelGGL(combine_kernel, dim3(ROWS * 32 / 256), dim3(256), 0, stream,
                       Opart, Lpart, out);
}

// Round 8
// 193.997 us; speedup vs baseline: 1.4225x; 1.1819x over previous
//
#include <hip/hip_runtime.h>
#include <hip/hip_bf16.h>

// CrossAttentionHead: B=8, S=2048, E=768, H=128. fp32 inputs AND fp32 output.
// q=x@Wq+bq; k=x@Wk+bk; v=x@Wv+bv; out = softmax(q k^T / sqrt(768)) @ v
// enc_output (d_in[1]) unused. Intermediates bf16, accum fp32.
// R8: revert to R5 structures (best measured: qkv 47.6us, flash ~45us).
//     One change: flash 32 q-rows/wave (128 q/block, 512 blocks, 2/CU,
//     launch_bounds(256,2)): kf/vf reused across 2 q-subtiles from regs ->
//     LDS reads per MFMA halve (36/34 -> 38/68). R7's global-Q is dead
//     (FETCH 109MB: Q re-reads miss L2); R6's manual prefetch is dead (spill).

typedef __bf16 bf16x8 __attribute__((ext_vector_type(8)));
typedef float f32x4 __attribute__((ext_vector_type(4)));
using bf16 = __hip_bfloat16;

#define EMB 768
#define HD 128
#define SEQ 2048
#define BATCH 8
#define ROWS (BATCH * SEQ)   // 16384
#define NSPLIT 4
#define TILES_PER_SPLIT (SEQ / 64 / NSPLIT)  // 8

// convert 8 fp32 -> 8 bf16, single 16B store
__device__ inline void cvt_store8(bf16* dst, float4 a, float4 b) {
    union { bf16 h[8]; uint4 u; } t;
    t.h[0] = __float2bfloat16(a.x); t.h[1] = __float2bfloat16(a.y);
    t.h[2] = __float2bfloat16(a.z); t.h[3] = __float2bfloat16(a.w);
    t.h[4] = __float2bfloat16(b.x); t.h[5] = __float2bfloat16(b.y);
    t.h[6] = __float2bfloat16(b.z); t.h[7] = __float2bfloat16(b.w);
    *reinterpret_cast<uint4*>(dst) = t.u;
}

// ---------------------------------------------------------------- W transpose
__global__ __launch_bounds__(256) void wt_kernel(
    const float* __restrict__ Wq, const float* __restrict__ Wk,
    const float* __restrict__ Wv, bf16* __restrict__ Wt)
{
    __shared__ float t_lds[32][33];
    const int tid = threadIdx.x;
    const int k0 = blockIdx.x * 32;
    const int n0 = blockIdx.y * 32;
    const int mtx = blockIdx.z;
    const float* W = (mtx == 0) ? Wq : (mtx == 1) ? Wk : Wv;
    const int j = tid & 31, i0 = tid >> 5;
#pragma unroll
    for (int c = 0; c < 4; ++c)
        t_lds[i0 + 8 * c][j] = W[(size_t)(k0 + i0 + 8 * c) * HD + n0 + j];
    __syncthreads();
#pragma unroll
    for (int c = 0; c < 4; ++c)
        Wt[(size_t)mtx * HD * EMB + (size_t)(n0 + i0 + 8 * c) * EMB + k0 + j] =
            __float2bfloat16(t_lds[j][i0 + 8 * c]);
}

// ---------------------------------------------------------------- QKV GEMM (R5-proven)
// grid (256 row-tiles, 3 sel), block 256 (4 waves). Tile 64(M)x128(N), BK=64.
__global__ __launch_bounds__(256) void qkv_kernel(
    const float* __restrict__ x, const bf16* __restrict__ Wt,
    const float* __restrict__ bq, const float* __restrict__ bk,
    const float* __restrict__ bv,
    bf16* __restrict__ Q, bf16* __restrict__ K, bf16* __restrict__ Vt)
{
    __shared__ alignas(16) bf16 a_lds[64][68];
    __shared__ alignas(16) bf16 b_lds[128][68];
    const int tid  = threadIdx.x;
    const int sel  = blockIdx.y;
    const int row0 = blockIdx.x * 64;
    const bf16* Wsel = Wt + (size_t)sel * HD * EMB;
    const int lane = tid & 63, wave = tid >> 6;
    const int lr = lane & 15, lq = lane >> 4;

    f32x4 acc[8];
#pragma unroll
    for (int j = 0; j < 8; ++j) acc[j] = f32x4{0.f, 0.f, 0.f, 0.f};

    for (int kt = 0; kt < EMB / 64; ++kt) {
#pragma unroll
        for (int c = 0; c < 2; ++c) {
            int lin = tid + c * 256;
            int r = lin >> 3, ch = lin & 7;
            const float* src = &x[(size_t)(row0 + r) * EMB + kt * 64 + ch * 8];
            float4 f0 = *reinterpret_cast<const float4*>(src);
            float4 f1 = *reinterpret_cast<const float4*>(src + 4);
            cvt_store8(&a_lds[r][ch * 8], f0, f1);
        }
#pragma unroll
        for (int c = 0; c < 4; ++c) {
            int lin = tid + c * 256;
            int r = lin >> 3, ch = lin & 7;
            *reinterpret_cast<uint4*>(&b_lds[r][ch * 8]) =
                *reinterpret_cast<const uint4*>(&Wsel[(size_t)r * EMB + kt * 64 + ch * 8]);
        }
        __syncthreads();
#pragma unroll
        for (int ks = 0; ks < 2; ++ks) {
            bf16x8 a = *reinterpret_cast<const bf16x8*>(&a_lds[wave * 16 + lr][ks * 32 + lq * 8]);
#pragma unroll
            for (int nt = 0; nt < 8; ++nt) {
                bf16x8 b = *reinterpret_cast<const bf16x8*>(&b_lds[nt * 16 + lr][ks * 32 + lq * 8]);
                acc[nt] = __builtin_amdgcn_mfma_f32_16x16x32_bf16(a, b, acc[nt], 0, 0, 0);
            }
        }
        __syncthreads();
    }

    bf16 (*o_lds)[132] = reinterpret_cast<bf16(*)[132]>(&b_lds[0][0]);
    const float* bias = (sel == 0) ? bq : (sel == 1) ? bk : bv;
#pragma unroll
    for (int nt = 0; nt < 8; ++nt) {
        int col = nt * 16 + lr;
        float bb = bias[col];
#pragma unroll
        for (int rg = 0; rg < 4; ++rg)
            o_lds[wave * 16 + lq * 4 + rg][col] = __float2bfloat16(acc[nt][rg] + bb);
    }
    __syncthreads();
    if (sel < 2) {
        bf16* dst = (sel == 0) ? Q : K;
#pragma unroll
        for (int c = 0; c < 4; ++c) {
            int lin = tid + c * 256;
            int r = lin >> 4, ch = lin & 15;
            *reinterpret_cast<uint4*>(&dst[(size_t)(row0 + r) * HD + ch * 8]) =
                *reinterpret_cast<const uint4*>(&o_lds[r][ch * 8]);
        }
    } else {
        int d = tid >> 1, sh = (tid & 1) * 32;
        int bi = row0 >> 11, s0 = row0 & (SEQ - 1);
        union { bf16 h[32]; uint4 u4[4]; } pk;
#pragma unroll
        for (int s = 0; s < 32; ++s) pk.h[s] = o_lds[sh + s][d];
        bf16* base = &Vt[((size_t)bi * HD + d) * SEQ + s0 + sh];
#pragma unroll
        for (int c = 0; c < 4; ++c)
            *reinterpret_cast<uint4*>(base + c * 8) = pk.u4[c];
    }
}

// ---------------------------------------------------------------- flash attn (split-K, S^T, 32q/wave)
// grid (16 q-tiles, 8 batches, 4 splits) = 512 blocks; block 256 = 4 waves x 32 q.
// S^T = K q^T (fixed-shift exp2), O^T = V^T P^T; l via ones-row at d=128.
// kf/vf LDS fragments reused across 2 q-subtiles from registers.
__global__ __launch_bounds__(256, 2) void flash_kernel(
    const bf16* __restrict__ Q, const bf16* __restrict__ K,
    const bf16* __restrict__ Vt,
    float* __restrict__ Opart, float* __restrict__ Lpart)
{
    __shared__ alignas(16) bf16 k_lds[64][132];      // [krow][d]      16.9 KB
    __shared__ alignas(16) bf16 v_lds[144][68];      // [d][krow]+ones 19.6 KB
    __shared__ alignas(16) bf16 p_lds[4][32][72];    // per-wave P^T   18.4 KB
    const int tid = threadIdx.x;
    const int lane = tid & 63, wave = tid >> 6;
    const int lr = lane & 15, lq = lane >> 4;
    const int b  = blockIdx.y;
    const int split = blockIdx.z;
    const int q0 = blockIdx.x * 128;
    const int qrow = b * SEQ + q0 + wave * 32;       // wave's 32-q base

    const float sc = 0.03608439182435161f * 1.44269504088896f; // 1/sqrt(768)*log2(e)

    // ones-row block for l: v_lds row 128 = 1.0, rows 129..143 = 0 (written once)
    for (int i = tid; i < 16 * 68; i += 256) {
        int r = i / 68, c = i % 68;
        v_lds[128 + r][c] = __float2bfloat16(r == 0 ? 1.0f : 0.0f);
    }

    bf16x8 qf[2][4];                                  // 2 q-subtiles x 4 k-steps
#pragma unroll
    for (int qt = 0; qt < 2; ++qt)
#pragma unroll
        for (int ks = 0; ks < 4; ++ks)
            qf[qt][ks] = *reinterpret_cast<const bf16x8*>(
                &Q[(size_t)(qrow + qt * 16 + lr) * HD + ks * 32 + lq * 8]);

    f32x4 o[2][9];
#pragma unroll
    for (int qt = 0; qt < 2; ++qt)
#pragma unroll
        for (int d = 0; d < 9; ++d) o[qt][d] = f32x4{0.f, 0.f, 0.f, 0.f};

    for (int t = split * TILES_PER_SPLIT; t < (split + 1) * TILES_PER_SPLIT; ++t) {
        __syncthreads();                             // prev iter's LDS reads done (covers init)
#pragma unroll
        for (int c = 0; c < 4; ++c) {                // K tile: 64 rows x 128 d
            int lin = tid + c * 256;
            int r = lin >> 4, ch = lin & 15;
            *reinterpret_cast<uint4*>(&k_lds[r][ch * 8]) =
                *reinterpret_cast<const uint4*>(&K[(size_t)(b * SEQ + t * 64 + r) * HD + ch * 8]);
        }
#pragma unroll
        for (int c = 0; c < 4; ++c) {                // Vt tile: 128 d x 64 krow
            int lin = tid + c * 256;
            int r = lin >> 3, ch = lin & 7;
            *reinterpret_cast<uint4*>(&v_lds[r][ch * 8]) =
                *reinterpret_cast<const uint4*>(&Vt[((size_t)b * HD + r) * SEQ + t * 64 + ch * 8]);
        }
        __syncthreads();

        // S^T per k-subtile nt: kf loaded once, reused for both q-subtiles.
        // s layout: lane holds q = qt*16+lr, k = nt*16+lq*4+r
#pragma unroll
        for (int nt = 0; nt < 4; ++nt) {
            bf16x8 kf[4];
#pragma unroll
            for (int ks = 0; ks < 4; ++ks)
                kf[ks] = *reinterpret_cast<const bf16x8*>(&k_lds[nt * 16 + lr][ks * 32 + lq * 8]);
#pragma unroll
            for (int qt = 0; qt < 2; ++qt) {
                f32x4 s = f32x4{0.f, 0.f, 0.f, 0.f};
#pragma unroll
                for (int ks = 0; ks < 4; ++ks)
                    s = __builtin_amdgcn_mfma_f32_16x16x32_bf16(kf[ks], qf[qt][ks], s, 0, 0, 0);
                union { bf16 h[4]; uint2 u; } pk;
#pragma unroll
                for (int r = 0; r < 4; ++r)
                    pk.h[r] = __float2bfloat16(exp2f(__builtin_fmaf(s[r], sc, -8.0f)));
                *reinterpret_cast<uint2*>(&p_lds[wave][qt * 16 + lr][nt * 16 + lq * 4]) = pk.u;
            }
        }
        // wave-private p region: no barrier needed

        // O^T += V^T P^T : vf loaded once per (d,ks), reused for both q-subtiles
#pragma unroll
        for (int ks = 0; ks < 2; ++ks) {
            bf16x8 pf[2];
#pragma unroll
            for (int qt = 0; qt < 2; ++qt)
                pf[qt] = *reinterpret_cast<const bf16x8*>(
                    &p_lds[wave][qt * 16 + lr][ks * 32 + lq * 8]);
#pragma unroll
            for (int d = 0; d < 9; ++d) {
                bf16x8 vf = *reinterpret_cast<const bf16x8*>(&v_lds[d * 16 + lr][ks * 32 + lq * 8]);
#pragma unroll
                for (int qt = 0; qt < 2; ++qt)
                    o[qt][d] = __builtin_amdgcn_mfma_f32_16x16x32_bf16(vf, pf[qt], o[qt][d], 0, 0, 0);
            }
        }
    }

    // O^T frag: q = qrow+qt*16+lr, d = dtile*16 + lq*4 + reg  -> float4 stores
    const size_t obase = (size_t)split * ROWS;
#pragma unroll
    for (int qt = 0; qt < 2; ++qt) {
#pragma unroll
        for (int d = 0; d < 8; ++d)
            *reinterpret_cast<f32x4*>(
                &Opart[(obase + qrow + qt * 16 + lr) * HD + d * 16 + lq * 4]) = o[qt][d];
        if (lane < 16)                               // lq==0, reg 0 of tile 8 = l(q)
            Lpart[obase + qrow + qt * 16 + lr] = o[qt][8][0];
    }
}

// ---------------------------------------------------------------- combine
__global__ __launch_bounds__(256) void combine_kernel(
    const float* __restrict__ Opart, const float* __restrict__ Lpart,
    float* __restrict__ out)
{
    int gid = blockIdx.x * 256 + threadIdx.x;      // ROWS * 32
    int row = gid >> 5, dc = gid & 31;
    float L = 0.f;
#pragma unroll
    for (int s = 0; s < NSPLIT; ++s)
        L += Lpart[(size_t)s * ROWS + row];
    float4 acc = {0.f, 0.f, 0.f, 0.f};
#pragma unroll
    for (int s = 0; s < NSPLIT; ++s) {
        float4 v = *reinterpret_cast<const float4*>(&Opart[((size_t)s * ROWS + row) * HD + dc * 4]);
        acc.x += v.x; acc.y += v.y; acc.z += v.z; acc.w += v.w;
    }
    float inv = 1.f / L;
    acc.x *= inv; acc.y *= inv; acc.z *= inv; acc.w *= inv;
    *reinterpret_cast<float4*>(&out[(size_t)row * HD + dc * 4]) = acc;
}

// ---------------------------------------------------------------- launch
extern "C" void kernel_launch(void* const* d_in, const int* in_sizes, int n_in,
                              void* d_out, int out_size, void* d_ws, size_t ws_size,
                              hipStream_t stream) {
    const float* x  = (const float*)d_in[0];
    const float* Wq = (const float*)d_in[2];
    const float* bq = (const float*)d_in[3];
    const float* Wk = (const float*)d_in[4];
    const float* bk = (const float*)d_in[5];
    const float* Wv = (const float*)d_in[6];
    const float* bv = (const float*)d_in[7];
    float* out = (float*)d_out;

    char* ws = (char*)d_ws;
    const size_t WT_BYTES  = (size_t)3 * HD * EMB * 2;
    const size_t QKV_BYTES = (size_t)ROWS * HD * 2;
    const size_t OP_BYTES  = (size_t)NSPLIT * ROWS * HD * 4;
    bf16*  Wt    = (bf16*)ws;
    bf16*  Qb    = (bf16*)(ws + WT_BYTES);
    bf16*  Kb    = (bf16*)(ws + WT_BYTES + QKV_BYTES);
    bf16*  Vt    = (bf16*)(ws + WT_BYTES + 2 * QKV_BYTES);
    float* Opart = (float*)(ws + WT_BYTES + 3 * QKV_BYTES);
    float* Lpart = (float*)(ws + WT_BYTES + 3 * QKV_BYTES + OP_BYTES);

    hipLaunchKernelGGL(wt_kernel, dim3(EMB / 32, HD / 32, 3), dim3(256), 0, stream,
                       Wq, Wk, Wv, Wt);
    hipLaunchKernelGGL(qkv_kernel, dim3(ROWS / 64, 3), dim3(256), 0, stream,
                       x, Wt, bq, bk, bv, Qb, Kb, Vt);
    hipLaunchKernelGGL(flash_kernel, dim3(SEQ / 128, BATCH, NSPLIT), dim3(256), 0, stream,
                       Qb, Kb, Vt, Opart, Lpart);
    hipLaunchKernelGGL(combine_kernel, dim3(ROWS * 32 / 256), dim3(256), 0, stream,
                       Opart, Lpart, out);
}